// Round 26
// baseline (42.979 us; speedup 1.0000x reference)
//
#include <hip/hip_runtime.h>
#include <cstdint>
#include <cstddef>

// ContrastiveLoss: B=8192, D=256 fp32 inputs.
// loss = mean_b [ log( exp(2*pos_b) + sum_c exp(2*z_i[b].z_k[c]) ) - 2*pos_b ]
// R25: R24 + accumulator dependency-chain split: per 4-step tile, kt={0,1}
// accumulate into accA and kt={2,3} into accB (independent MFMA chains,
// depth 2 instead of 4; merged at the exp2 epilogue). +16 VGPR, expected to
// stay in the <=128-reg 16-wave occupancy bin. Everything else identical to
// R24 (verified): fp8-MX 32x32 wave tile, A in regs, B ring depth 4,
// contiguous 32B/lane frags, row-fast grid, no LDS/barriers; prep v2;
// two-stage finalize.

constexpr int   D_DIM = 256;
constexpr float INV_T = 2.0f;        // 1/T, T=0.5
constexpr float LOG2E = 1.44269504f;

constexpr int BM = 128;         // block rows
constexpr int NT = 16;          // col-tiles per block (each 32 cols)

typedef __attribute__((ext_vector_type(8)))  int   i32x8;
typedef __attribute__((ext_vector_type(16))) float f32x16;

// ---------------------------------------------------------------------------
// Kernel 1 (v2, unchanged R24): 8 rows/block, 32 threads/row (each 8 elems).
// Contiguous pack: f = (row>>5)*4 + (c8>>3); lane = (row&31)+32*((c8>>2)&1);
// byte = f*2048 + lane*32 + ((c8>>1)&1)*16 + (c8&1)*8.
// z_i scaled by LOG2E (GEMM scale-A=2.0 then yields exp2 argument).
// ---------------------------------------------------------------------------
__global__ __launch_bounds__(256) void prep_kernel(
    const float* __restrict__ ei, const float* __restrict__ ej,
    const float* __restrict__ ek,
    unsigned char* __restrict__ zip, unsigned char* __restrict__ zkp,
    float* __restrict__ pos_logit, float* __restrict__ rowsum)
{
    const int t   = (int)threadIdx.x;
    const int rl  = t >> 5;             // row within block (0..7)
    const int c8  = t & 31;             // 8-elem chunk (0..31)
    const int row = (int)blockIdx.x * 8 + rl;

    const float4* pi = (const float4*)(ei + (size_t)row * D_DIM + c8 * 8);
    const float4* pj = (const float4*)(ej + (size_t)row * D_DIM + c8 * 8);
    const float4* pk = (const float4*)(ek + (size_t)row * D_DIM + c8 * 8);
    float4 vi[2], vj[2], vk[2];
    #pragma unroll
    for (int q = 0; q < 2; ++q) { vi[q] = pi[q]; vj[q] = pj[q]; vk[q] = pk[q]; }

    float ssi = 0.f, ssj = 0.f, ssk = 0.f, dij = 0.f;
    #pragma unroll
    for (int q = 0; q < 2; ++q) {
        ssi += vi[q].x*vi[q].x + vi[q].y*vi[q].y + vi[q].z*vi[q].z + vi[q].w*vi[q].w;
        ssj += vj[q].x*vj[q].x + vj[q].y*vj[q].y + vj[q].z*vj[q].z + vj[q].w*vj[q].w;
        ssk += vk[q].x*vk[q].x + vk[q].y*vk[q].y + vk[q].z*vk[q].z + vk[q].w*vk[q].w;
        dij += vi[q].x*vj[q].x + vi[q].y*vj[q].y + vi[q].z*vj[q].z + vi[q].w*vj[q].w;
    }
    #pragma unroll
    for (int off = 1; off <= 16; off <<= 1) {   // reduce over the 32 c8-lanes
        ssi += __shfl_xor(ssi, off);
        ssj += __shfl_xor(ssj, off);
        ssk += __shfl_xor(ssk, off);
        dij += __shfl_xor(dij, off);
    }
    const float rn = 1.0f / fmaxf(sqrtf(ssi), 1e-12f);
    const float ri = rn * LOG2E;                          // fold log2(e)
    const float rj = 1.0f / fmaxf(sqrtf(ssj), 1e-12f);
    const float rk = 1.0f / fmaxf(sqrtf(ssk), 1e-12f);

    uint2 uiv, ukv;
    {
        unsigned int wi[2], wk[2];
        #pragma unroll
        for (int q = 0; q < 2; ++q) {
            const float* fi = &vi[q].x;
            const float* fk = &vk[q].x;
            int a = 0, b = 0;
            a = __builtin_amdgcn_cvt_pk_fp8_f32(fi[0] * ri, fi[1] * ri, a, false);
            a = __builtin_amdgcn_cvt_pk_fp8_f32(fi[2] * ri, fi[3] * ri, a, true);
            b = __builtin_amdgcn_cvt_pk_fp8_f32(fk[0] * rk, fk[1] * rk, b, false);
            b = __builtin_amdgcn_cvt_pk_fp8_f32(fk[2] * rk, fk[3] * rk, b, true);
            wi[q] = (unsigned int)a;
            wk[q] = (unsigned int)b;
        }
        uiv = make_uint2(wi[0], wi[1]);
        ukv = make_uint2(wk[0], wk[1]);
    }
    const int f    = (row >> 5) * 4 + (c8 >> 3);
    const int lane = (row & 31) + 32 * ((c8 >> 2) & 1);
    const size_t off = (size_t)f * 2048 + lane * 32
                     + ((c8 >> 1) & 1) * 16 + (c8 & 1) * 8;
    *(uint2*)(zip + off) = uiv;
    *(uint2*)(zkp + off) = ukv;

    if (c8 == 0) {
        pos_logit[row] = dij * rn * rj * INV_T;   // plain 2*(zi.zj), no log2e
        rowsum[row]    = 0.0f;
    }
}

// ---------------------------------------------------------------------------
// Kernel 2: rows [bR*128,+128) x cols [bC*512,+512); bR = blockIdx.x (FAST),
// bC = blockIdx.y. 4 waves = row slices; wave tile 32x32; 64 steps fully
// unrolled. A in regs; B ring depth 4. Dual accumulator chains (accA: kt 0,1;
// accB: kt 2,3) halve the dependent-MFMA chain depth. No LDS, no barriers.
// ---------------------------------------------------------------------------
__global__ __launch_bounds__(256) void sim_mfma_kernel(
    const unsigned char* __restrict__ zip, const unsigned char* __restrict__ zkp,
    float* __restrict__ rowsum)
{
    const int t  = (int)threadIdx.x;
    const int w  = t >> 6;        // wave 0..3 = row slice
    const int l  = t & 63;
    const int bR = (int)blockIdx.x;    // row block (fast)
    const int bC = (int)blockIdx.y;    // col block
    const int rowBase = bR * BM;

    const unsigned char* Abase =
        zip + ((size_t)(bR * 4 + w) * 4) * 2048 + (size_t)l * 32;
    i32x8 a0 = *(const i32x8*)(Abase);
    i32x8 a1 = *(const i32x8*)(Abase + 2048);
    i32x8 a2 = *(const i32x8*)(Abase + 4096);
    i32x8 a3 = *(const i32x8*)(Abase + 6144);

    const unsigned char* Bbase =
        zkp + ((size_t)bC * 16 * 4) * 2048 + (size_t)l * 32;

    i32x8 b0 = *(const i32x8*)(Bbase);
    i32x8 b1 = *(const i32x8*)(Bbase + 2048);
    i32x8 b2 = *(const i32x8*)(Bbase + 4096);
    i32x8 b3 = *(const i32x8*)(Bbase + 6144);

    float partAcc[16] = {};

    #pragma unroll
    for (int nt = 0; nt < NT; ++nt) {
        f32x16 accA = {};
        f32x16 accB = {};

        #pragma unroll
        for (int k4 = 0; k4 < 4; ++k4) {
            const int s  = nt * 4 + k4;           // compile-time
            const int s4 = (s + 4 > NT * 4 - 1) ? (NT * 4 - 1) : (s + 4);

            __builtin_amdgcn_s_setprio(1);
            if (k4 < 2) {
                accA = __builtin_amdgcn_mfma_scale_f32_32x32x64_f8f6f4(
                    (k4 == 0) ? a0 : a1,
                    (s % 4 == 0) ? b0 : (s % 4 == 1) ? b1
                                 : (s % 4 == 2) ? b2 : b3,
                    accA,
                    0, 0, 0, 0x00000080, 0, 0x0000007F);
            } else {
                accB = __builtin_amdgcn_mfma_scale_f32_32x32x64_f8f6f4(
                    (k4 == 2) ? a2 : a3,
                    (s % 4 == 0) ? b0 : (s % 4 == 1) ? b1
                                 : (s % 4 == 2) ? b2 : b3,
                    accB,
                    0, 0, 0, 0x00000080, 0, 0x0000007F);
            }
            __builtin_amdgcn_s_setprio(0);

            if (s % 4 == 0)      { b0 = *(const i32x8*)(Bbase + (size_t)s4 * 2048); }
            else if (s % 4 == 1) { b1 = *(const i32x8*)(Bbase + (size_t)s4 * 2048); }
            else if (s % 4 == 2) { b2 = *(const i32x8*)(Bbase + (size_t)s4 * 2048); }
            else                 { b3 = *(const i32x8*)(Bbase + (size_t)s4 * 2048); }
        }

        // per-tile epilogue: merge chains + bare exp2 + in-lane partial sums
        #pragma unroll
        for (int r = 0; r < 16; ++r)
            partAcc[r] += exp2f(accA[r] + accB[r]);
    }

    #pragma unroll
    for (int off = 1; off <= 16; off <<= 1)
        #pragma unroll
        for (int r = 0; r < 16; ++r)
            partAcc[r] += __shfl_xor(partAcc[r], off);

    if ((l & 31) == 0) {
        const int hi = l >> 5;           // C/D: row = (r&3) + 8*(r>>2) + 4*hi
        #pragma unroll
        for (int r = 0; r < 16; ++r) {
            const int rr = (r & 3) + 8 * (r >> 2) + 4 * hi;
            atomicAdd(&rowsum[rowBase + w * 32 + rr], partAcc[r]);
        }
    }
}

// ---------------------------------------------------------------------------
// Kernel 3a: stage-1 reduce — 32 blocks x 256 threads, one row per thread.
// ---------------------------------------------------------------------------
__global__ __launch_bounds__(256) void finalize1_kernel(
    const float* __restrict__ pos_logit, const float* __restrict__ rowsum,
    float* __restrict__ partial)
{
    __shared__ float red[256];
    const int b = (int)blockIdx.x * 256 + (int)threadIdx.x;
    const float pl = pos_logit[b];
    red[threadIdx.x] = logf(expf(pl) + rowsum[b]) - pl;
    __syncthreads();
    #pragma unroll
    for (int s = 128; s; s >>= 1) {
        if ((int)threadIdx.x < s) red[threadIdx.x] += red[threadIdx.x + s];
        __syncthreads();
    }
    if (threadIdx.x == 0) partial[blockIdx.x] = red[0];
}

// ---------------------------------------------------------------------------
// Kernel 3b: stage-2 — one wave sums 32 partials, writes mean.
// ---------------------------------------------------------------------------
__global__ __launch_bounds__(64) void finalize2_kernel(
    const float* __restrict__ partial, float* __restrict__ out, int B)
{
    const int l = (int)threadIdx.x;
    float v = (l < 32) ? partial[l] : 0.0f;
    #pragma unroll
    for (int off = 1; off <= 16; off <<= 1)
        v += __shfl_xor(v, off);
    if (l == 0) out[0] = v / (float)B;
}

// ---------------------------------------------------------------------------
extern "C" void kernel_launch(void* const* d_in, const int* in_sizes, int n_in,
                              void* d_out, int out_size, void* d_ws, size_t ws_size,
                              hipStream_t stream)
{
    const float* ei = (const float*)d_in[0];
    const float* ej = (const float*)d_in[1];
    const float* ek = (const float*)d_in[2];
    const int B = in_sizes[0] / D_DIM;   // 8192

    unsigned char* zip = (unsigned char*)d_ws;              // 2 MB packed fp8
    unsigned char* zkp = zip + (size_t)B * D_DIM;           // 2 MB packed fp8
    float* rowsum      = (float*)(zkp + (size_t)B * D_DIM);
    float* pos_logit   = rowsum + B;
    float* partial     = pos_logit + B;                     // 32 floats

    prep_kernel<<<dim3(B / 8), dim3(256), 0, stream>>>(
        ei, ej, ek, zip, zkp, pos_logit, rowsum);

    dim3 grid(B / BM, B / (NT * 32));    // (64, 16) = 1024 blocks
    sim_mfma_kernel<<<grid, dim3(256), 0, stream>>>(zip, zkp, rowsum);

    finalize1_kernel<<<dim3(B / 256), dim3(256), 0, stream>>>(
        pos_logit, rowsum, partial);
    finalize2_kernel<<<dim3(1), dim3(64), 0, stream>>>(
        partial, (float*)d_out, B);
}

// Round 27
// 40.617 us; speedup vs baseline: 1.0581x; 1.0581x over previous
//
#include <hip/hip_runtime.h>
#include <cstdint>
#include <cstddef>

// ContrastiveLoss: B=8192, D=256 fp32 inputs.
// loss = mean_b [ log( exp(2*pos_b) + sum_c exp(2*z_i[b].z_k[c]) ) - 2*pos_b ]
// R26 = R24 (best measured, 41.07 us): fp8-MX MFMA sim (32x32 wave tile,
// A in regs, B ring depth 4, contiguous 32B/lane frags, row-fast grid,
// no LDS/barriers, <=128-reg occupancy bin), prep v2 (32 thr/row),
// two-stage finalize. R25's dual-acc split reverted (regressed).

constexpr int   D_DIM = 256;
constexpr float INV_T = 2.0f;        // 1/T, T=0.5
constexpr float LOG2E = 1.44269504f;

constexpr int BM = 128;         // block rows
constexpr int NT = 16;          // col-tiles per block (each 32 cols)

typedef __attribute__((ext_vector_type(8)))  int   i32x8;
typedef __attribute__((ext_vector_type(16))) float f32x16;

// ---------------------------------------------------------------------------
// Kernel 1 (v2): 8 rows/block, 32 threads/row (each 8 elems).
// Contiguous pack: f = (row>>5)*4 + (c8>>3); lane = (row&31)+32*((c8>>2)&1);
// byte = f*2048 + lane*32 + ((c8>>1)&1)*16 + (c8&1)*8.
// z_i scaled by LOG2E (GEMM scale-A=2.0 then yields exp2 argument).
// ---------------------------------------------------------------------------
__global__ __launch_bounds__(256) void prep_kernel(
    const float* __restrict__ ei, const float* __restrict__ ej,
    const float* __restrict__ ek,
    unsigned char* __restrict__ zip, unsigned char* __restrict__ zkp,
    float* __restrict__ pos_logit, float* __restrict__ rowsum)
{
    const int t   = (int)threadIdx.x;
    const int rl  = t >> 5;             // row within block (0..7)
    const int c8  = t & 31;             // 8-elem chunk (0..31)
    const int row = (int)blockIdx.x * 8 + rl;

    const float4* pi = (const float4*)(ei + (size_t)row * D_DIM + c8 * 8);
    const float4* pj = (const float4*)(ej + (size_t)row * D_DIM + c8 * 8);
    const float4* pk = (const float4*)(ek + (size_t)row * D_DIM + c8 * 8);
    float4 vi[2], vj[2], vk[2];
    #pragma unroll
    for (int q = 0; q < 2; ++q) { vi[q] = pi[q]; vj[q] = pj[q]; vk[q] = pk[q]; }

    float ssi = 0.f, ssj = 0.f, ssk = 0.f, dij = 0.f;
    #pragma unroll
    for (int q = 0; q < 2; ++q) {
        ssi += vi[q].x*vi[q].x + vi[q].y*vi[q].y + vi[q].z*vi[q].z + vi[q].w*vi[q].w;
        ssj += vj[q].x*vj[q].x + vj[q].y*vj[q].y + vj[q].z*vj[q].z + vj[q].w*vj[q].w;
        ssk += vk[q].x*vk[q].x + vk[q].y*vk[q].y + vk[q].z*vk[q].z + vk[q].w*vk[q].w;
        dij += vi[q].x*vj[q].x + vi[q].y*vj[q].y + vi[q].z*vj[q].z + vi[q].w*vj[q].w;
    }
    #pragma unroll
    for (int off = 1; off <= 16; off <<= 1) {   // reduce over the 32 c8-lanes
        ssi += __shfl_xor(ssi, off);
        ssj += __shfl_xor(ssj, off);
        ssk += __shfl_xor(ssk, off);
        dij += __shfl_xor(dij, off);
    }
    const float rn = 1.0f / fmaxf(sqrtf(ssi), 1e-12f);
    const float ri = rn * LOG2E;                          // fold log2(e)
    const float rj = 1.0f / fmaxf(sqrtf(ssj), 1e-12f);
    const float rk = 1.0f / fmaxf(sqrtf(ssk), 1e-12f);

    uint2 uiv, ukv;
    {
        unsigned int wi[2], wk[2];
        #pragma unroll
        for (int q = 0; q < 2; ++q) {
            const float* fi = &vi[q].x;
            const float* fk = &vk[q].x;
            int a = 0, b = 0;
            a = __builtin_amdgcn_cvt_pk_fp8_f32(fi[0] * ri, fi[1] * ri, a, false);
            a = __builtin_amdgcn_cvt_pk_fp8_f32(fi[2] * ri, fi[3] * ri, a, true);
            b = __builtin_amdgcn_cvt_pk_fp8_f32(fk[0] * rk, fk[1] * rk, b, false);
            b = __builtin_amdgcn_cvt_pk_fp8_f32(fk[2] * rk, fk[3] * rk, b, true);
            wi[q] = (unsigned int)a;
            wk[q] = (unsigned int)b;
        }
        uiv = make_uint2(wi[0], wi[1]);
        ukv = make_uint2(wk[0], wk[1]);
    }
    const int f    = (row >> 5) * 4 + (c8 >> 3);
    const int lane = (row & 31) + 32 * ((c8 >> 2) & 1);
    const size_t off = (size_t)f * 2048 + lane * 32
                     + ((c8 >> 1) & 1) * 16 + (c8 & 1) * 8;
    *(uint2*)(zip + off) = uiv;
    *(uint2*)(zkp + off) = ukv;

    if (c8 == 0) {
        pos_logit[row] = dij * rn * rj * INV_T;   // plain 2*(zi.zj), no log2e
        rowsum[row]    = 0.0f;
    }
}

// ---------------------------------------------------------------------------
// Kernel 2: rows [bR*128,+128) x cols [bC*512,+512); bR = blockIdx.x (FAST),
// bC = blockIdx.y. 4 waves = row slices; wave tile 32x32; 64 steps fully
// unrolled. A in regs; B ring depth 4. No LDS, no barriers.
// ---------------------------------------------------------------------------
__global__ __launch_bounds__(256) void sim_mfma_kernel(
    const unsigned char* __restrict__ zip, const unsigned char* __restrict__ zkp,
    float* __restrict__ rowsum)
{
    const int t  = (int)threadIdx.x;
    const int w  = t >> 6;        // wave 0..3 = row slice
    const int l  = t & 63;
    const int bR = (int)blockIdx.x;    // row block (fast)
    const int bC = (int)blockIdx.y;    // col block
    const int rowBase = bR * BM;

    const unsigned char* Abase =
        zip + ((size_t)(bR * 4 + w) * 4) * 2048 + (size_t)l * 32;
    i32x8 a0 = *(const i32x8*)(Abase);
    i32x8 a1 = *(const i32x8*)(Abase + 2048);
    i32x8 a2 = *(const i32x8*)(Abase + 4096);
    i32x8 a3 = *(const i32x8*)(Abase + 6144);

    const unsigned char* Bbase =
        zkp + ((size_t)bC * 16 * 4) * 2048 + (size_t)l * 32;

    i32x8 b0 = *(const i32x8*)(Bbase);
    i32x8 b1 = *(const i32x8*)(Bbase + 2048);
    i32x8 b2 = *(const i32x8*)(Bbase + 4096);
    i32x8 b3 = *(const i32x8*)(Bbase + 6144);

    float partAcc[16] = {};

    #pragma unroll
    for (int nt = 0; nt < NT; ++nt) {
        f32x16 acc = {};

        #pragma unroll
        for (int k4 = 0; k4 < 4; ++k4) {
            const int s  = nt * 4 + k4;           // compile-time
            const int s4 = (s + 4 > NT * 4 - 1) ? (NT * 4 - 1) : (s + 4);

            __builtin_amdgcn_s_setprio(1);
            acc = __builtin_amdgcn_mfma_scale_f32_32x32x64_f8f6f4(
                (k4 == 0) ? a0 : (k4 == 1) ? a1 : (k4 == 2) ? a2 : a3,
                (s % 4 == 0) ? b0 : (s % 4 == 1) ? b1
                             : (s % 4 == 2) ? b2 : b3,
                acc,
                0, 0,                 // cbsz=fp8(A), blgp=fp8(B)
                0, 0x00000080,        // scale A = 2.0 (1/T)
                0, 0x0000007F);       // scale B = 1.0
            __builtin_amdgcn_s_setprio(0);

            if (s % 4 == 0)      { b0 = *(const i32x8*)(Bbase + (size_t)s4 * 2048); }
            else if (s % 4 == 1) { b1 = *(const i32x8*)(Bbase + (size_t)s4 * 2048); }
            else if (s % 4 == 2) { b2 = *(const i32x8*)(Bbase + (size_t)s4 * 2048); }
            else                 { b3 = *(const i32x8*)(Bbase + (size_t)s4 * 2048); }
        }

        #pragma unroll
        for (int r = 0; r < 16; ++r)
            partAcc[r] += exp2f(acc[r]);
    }

    #pragma unroll
    for (int off = 1; off <= 16; off <<= 1)
        #pragma unroll
        for (int r = 0; r < 16; ++r)
            partAcc[r] += __shfl_xor(partAcc[r], off);

    if ((l & 31) == 0) {
        const int hi = l >> 5;           // C/D: row = (r&3) + 8*(r>>2) + 4*hi
        #pragma unroll
        for (int r = 0; r < 16; ++r) {
            const int rr = (r & 3) + 8 * (r >> 2) + 4 * hi;
            atomicAdd(&rowsum[rowBase + w * 32 + rr], partAcc[r]);
        }
    }
}

// ---------------------------------------------------------------------------
// Kernel 3a: stage-1 reduce — 32 blocks x 256 threads, one row per thread.
// ---------------------------------------------------------------------------
__global__ __launch_bounds__(256) void finalize1_kernel(
    const float* __restrict__ pos_logit, const float* __restrict__ rowsum,
    float* __restrict__ partial)
{
    __shared__ float red[256];
    const int b = (int)blockIdx.x * 256 + (int)threadIdx.x;
    const float pl = pos_logit[b];
    red[threadIdx.x] = logf(expf(pl) + rowsum[b]) - pl;
    __syncthreads();
    #pragma unroll
    for (int s = 128; s; s >>= 1) {
        if ((int)threadIdx.x < s) red[threadIdx.x] += red[threadIdx.x + s];
        __syncthreads();
    }
    if (threadIdx.x == 0) partial[blockIdx.x] = red[0];
}

// ---------------------------------------------------------------------------
// Kernel 3b: stage-2 — one wave sums 32 partials, writes mean.
// ---------------------------------------------------------------------------
__global__ __launch_bounds__(64) void finalize2_kernel(
    const float* __restrict__ partial, float* __restrict__ out, int B)
{
    const int l = (int)threadIdx.x;
    float v = (l < 32) ? partial[l] : 0.0f;
    #pragma unroll
    for (int off = 1; off <= 16; off <<= 1)
        v += __shfl_xor(v, off);
    if (l == 0) out[0] = v / (float)B;
}

// ---------------------------------------------------------------------------
extern "C" void kernel_launch(void* const* d_in, const int* in_sizes, int n_in,
                              void* d_out, int out_size, void* d_ws, size_t ws_size,
                              hipStream_t stream)
{
    const float* ei = (const float*)d_in[0];
    const float* ej = (const float*)d_in[1];
    const float* ek = (const float*)d_in[2];
    const int B = in_sizes[0] / D_DIM;   // 8192

    unsigned char* zip = (unsigned char*)d_ws;              // 2 MB packed fp8
    unsigned char* zkp = zip + (size_t)B * D_DIM;           // 2 MB packed fp8
    float* rowsum      = (float*)(zkp + (size_t)B * D_DIM);
    float* pos_logit   = rowsum + B;
    float* partial     = pos_logit + B;                     // 32 floats

    prep_kernel<<<dim3(B / 8), dim3(256), 0, stream>>>(
        ei, ej, ek, zip, zkp, pos_logit, rowsum);

    dim3 grid(B / BM, B / (NT * 32));    // (64, 16) = 1024 blocks
    sim_mfma_kernel<<<grid, dim3(256), 0, stream>>>(zip, zkp, rowsum);

    finalize1_kernel<<<dim3(B / 256), dim3(256), 0, stream>>>(
        pos_logit, rowsum, partial);
    finalize2_kernel<<<dim3(1), dim3(64), 0, stream>>>(
        partial, (float*)d_out, B);
}